// Round 1
// baseline (116.438 us; speedup 1.0000x reference)
//
#include <hip/hip_runtime.h>
#include <math.h>

#define N 512
#define SIGMA 0.5f
#define EPS 1e-7f

// ---------------------------------------------------------------------------
// Kernel 1: per-row squared norms. One wave (64 lanes) per row.
// ---------------------------------------------------------------------------
__global__ void sqnorm_kernel(const float* __restrict__ feat,
                              float* __restrict__ sqn) {
    int row = blockIdx.x;
    int lane = threadIdx.x;                 // 0..63
    const float* f = feat + row * N;
    float s = 0.f;
    #pragma unroll
    for (int c = lane; c < N; c += 64) { float v = f[c]; s += v * v; }
    #pragma unroll
    for (int off = 32; off > 0; off >>= 1) s += __shfl_down(s, off);
    if (lane == 0) sqn[row] = s;
}

// ---------------------------------------------------------------------------
// Kernel 2: Gram matrix -> F[i,j] = -SIGMA * sqrt(max(ni+nj-2*dot, 0)),
// diagonal forced to exactly 0. Tiled SGEMM, 32x32 tile, 16x16 threads,
// 2x2 micro-tile per thread.
// ---------------------------------------------------------------------------
__global__ void fmat_kernel(const float* __restrict__ feat,
                            const float* __restrict__ sqn,
                            float* __restrict__ Fm) {
    __shared__ float As[32][33];   // +1 pad: no bank conflicts
    __shared__ float Bs[32][33];
    const int tx = threadIdx.x;    // 0..15
    const int ty = threadIdx.y;    // 0..15
    const int r0 = blockIdx.y * 32;
    const int c0 = blockIdx.x * 32;
    const int t  = ty * 16 + tx;   // 0..255

    float acc00 = 0.f, acc01 = 0.f, acc10 = 0.f, acc11 = 0.f;

    for (int k0 = 0; k0 < N; k0 += 32) {
        #pragma unroll
        for (int l = 0; l < 4; ++l) {
            int idx = t + l * 256;        // 0..1023
            int rr = idx >> 5, cc = idx & 31;
            As[rr][cc] = feat[(r0 + rr) * N + k0 + cc];
            Bs[rr][cc] = feat[(c0 + rr) * N + k0 + cc];
        }
        __syncthreads();
        #pragma unroll
        for (int k = 0; k < 32; ++k) {
            float a0 = As[ty * 2][k],     a1 = As[ty * 2 + 1][k];
            float b0 = Bs[tx * 2][k],     b1 = Bs[tx * 2 + 1][k];
            acc00 += a0 * b0;  acc01 += a0 * b1;
            acc10 += a1 * b0;  acc11 += a1 * b1;
        }
        __syncthreads();
    }

    float accs[2][2] = {{acc00, acc01}, {acc10, acc11}};
    #pragma unroll
    for (int i = 0; i < 2; ++i) {
        #pragma unroll
        for (int j = 0; j < 2; ++j) {
            int r = r0 + ty * 2 + i;
            int c = c0 + tx * 2 + j;
            float sq = sqn[r] + sqn[c] - 2.f * accs[i][j];
            float v = (r == c) ? 0.f : -SIGMA * sqrtf(fmaxf(sq, 0.f));
            Fm[r * N + c] = v;
        }
    }
}

// ---------------------------------------------------------------------------
// Kernel 3: per-row fused softmax + denom + pos_log_probs sum.
// One block (512 threads) per row i. Thread t owns column/index t.
// ---------------------------------------------------------------------------
__global__ void row_kernel(const float* __restrict__ Fm,
                           const float* __restrict__ label,
                           float* __restrict__ rowsum) {
    const int i = blockIdx.x;
    const int t = threadIdx.x;   // 0..511

    __shared__ float Fs[N];      // shifted F row
    __shared__ float Ss[N];      // softmax row (S[i] zeroed after Z)
    __shared__ float Rs[N];      // |label_i - label_j|
    __shared__ float red[N];     // reduction scratch

    const float li = label[i];
    float f = Fm[i * N + t];
    Rs[t] = fabsf(li - label[t]);

    // --- row max (will be 0, but match reference exactly) ---
    red[t] = f;
    __syncthreads();
    #pragma unroll
    for (int off = 256; off > 0; off >>= 1) {
        if (t < off) red[t] = fmaxf(red[t], red[t + off]);
        __syncthreads();
    }
    const float m = red[0];
    __syncthreads();

    const float fsh = f - m;
    Fs[t] = fsh;
    const float e = __expf(fsh);

    // --- softmax denominator Z (includes diagonal term) ---
    red[t] = e;
    __syncthreads();
    #pragma unroll
    for (int off = 256; off > 0; off >>= 1) {
        if (t < off) red[t] += red[t + off];
        __syncthreads();
    }
    const float Z = red[0];
    __syncthreads();

    Ss[t] = e / Z;
    __syncthreads();
    if (t == i) Ss[i] = 0.f;     // exclude j==i from denom sums
    __syncthreads();

    // --- denom[k=t] = sum_j [R[j] >= R[k]] * S[j]  (branch-free) ---
    const float Rk = Rs[t];
    float denom = 0.f;
    #pragma unroll 8
    for (int j = 0; j < N; ++j) {
        // uniform broadcast reads across the wave: conflict-free
        denom += (Rs[j] >= Rk) ? Ss[j] : 0.f;
    }

    // --- per-k contribution; k==i excluded ---
    float part = (t == i) ? 0.f : (fsh - logf(denom + EPS));

    red[t] = part;
    __syncthreads();
    #pragma unroll
    for (int off = 256; off > 0; off >>= 1) {
        if (t < off) red[t] += red[t + off];
        __syncthreads();
    }
    if (t == 0) rowsum[i] = red[0];
}

// ---------------------------------------------------------------------------
// Kernel 4: final reduction over 512 row sums -> scalar loss.
// ---------------------------------------------------------------------------
__global__ void finalize_kernel(const float* __restrict__ rowsum,
                                float* __restrict__ out) {
    __shared__ float red[256];
    const int t = threadIdx.x;   // 0..255
    red[t] = rowsum[t] + rowsum[t + 256];
    __syncthreads();
    #pragma unroll
    for (int off = 128; off > 0; off >>= 1) {
        if (t < off) red[t] += red[t + off];
        __syncthreads();
    }
    if (t == 0) out[0] = -red[0] / (float)(N * (N - 1));
}

// ---------------------------------------------------------------------------
extern "C" void kernel_launch(void* const* d_in, const int* in_sizes, int n_in,
                              void* d_out, int out_size, void* d_ws, size_t ws_size,
                              hipStream_t stream) {
    const float* feature = (const float*)d_in[0];   // [512, 512] f32
    const float* label   = (const float*)d_in[1];   // [512, 1]  f32
    float* out = (float*)d_out;

    // workspace layout
    float* Fm     = (float*)d_ws;                    // N*N floats (1 MB)
    float* sqn    = Fm + (size_t)N * N;              // N floats
    float* rowsum = sqn + N;                         // N floats

    sqnorm_kernel<<<N, 64, 0, stream>>>(feature, sqn);
    {
        dim3 grid(N / 32, N / 32);
        dim3 block(16, 16);
        fmat_kernel<<<grid, block, 0, stream>>>(feature, sqn, Fm);
    }
    row_kernel<<<N, N, 0, stream>>>(Fm, label, rowsum);
    finalize_kernel<<<1, 256, 0, stream>>>(rowsum, out);
}

// Round 2
// 78.095 us; speedup vs baseline: 1.4910x; 1.4910x over previous
//
#include <hip/hip_runtime.h>
#include <math.h>

#define N 512
#define SIGMA 0.5f
#define EPS 1e-7f

typedef __attribute__((ext_vector_type(8))) short bf16x8;
typedef __attribute__((ext_vector_type(4))) float f32x4;

// ---------------------------------------------------------------------------
// Kernel 1: convert feature fp32 -> bf16 (RNE), per-row sq-norms of the
// ROUNDED values (consistency with the MFMA dot), zero the output scalar.
// One wave per row.
// ---------------------------------------------------------------------------
__device__ __forceinline__ unsigned short f2bf(float x) {
    unsigned int b = __float_as_uint(x);
    // round-to-nearest-even (inputs are finite randoms, no NaN path needed)
    b += 0x7FFFu + ((b >> 16) & 1u);
    return (unsigned short)(b >> 16);
}

__global__ void convert_kernel(const float* __restrict__ feat,
                               unsigned short* __restrict__ featb,
                               float* __restrict__ sqn,
                               float* __restrict__ out) {
    const int row = blockIdx.x;
    const int lane = threadIdx.x;            // 0..63
    if (row == 0 && lane == 0) out[0] = 0.f; // zero loss accumulator

    const float* f = feat + row * N;
    unsigned short* fb = featb + row * N;
    float s = 0.f;
    #pragma unroll
    for (int sweep = 0; sweep < 2; ++sweep) {
        int c = sweep * 256 + lane * 4;
        float4 v = *(const float4*)(f + c);
        unsigned short b0 = f2bf(v.x), b1 = f2bf(v.y), b2 = f2bf(v.z), b3 = f2bf(v.w);
        ushort4 packed = make_ushort4(b0, b1, b2, b3);
        *(ushort4*)(fb + c) = packed;
        // accumulate norms of the rounded values
        float r0 = __uint_as_float((unsigned int)b0 << 16);
        float r1 = __uint_as_float((unsigned int)b1 << 16);
        float r2 = __uint_as_float((unsigned int)b2 << 16);
        float r3 = __uint_as_float((unsigned int)b3 << 16);
        s += r0 * r0 + r1 * r1 + r2 * r2 + r3 * r3;
    }
    #pragma unroll
    for (int off = 32; off > 0; off >>= 1) s += __shfl_down(s, off);
    if (lane == 0) sqn[row] = s;
}

// ---------------------------------------------------------------------------
// Kernel 2: F matrix via bf16 MFMA Gram. One wave per 16x16 output tile.
// F[r,c] = -SIGMA * sqrt(max(n_r + n_c - 2*dot, 0)); diagonal forced to 0.
// Gram is symmetric, so any consistent fragment-layout transpose is benign.
// ---------------------------------------------------------------------------
__global__ void fmat_mfma_kernel(const unsigned short* __restrict__ featb,
                                 const float* __restrict__ sqn,
                                 float* __restrict__ Fm) {
    const int r0 = blockIdx.y * 16;
    const int c0 = blockIdx.x * 16;
    const int lane = threadIdx.x;            // 0..63
    const int m = lane & 15;                 // row within A tile / col within B tile
    const int kb = (lane >> 4) * 8;          // k-base for this lane's 8 elems

    const unsigned short* arow = featb + (size_t)(r0 + m) * N + kb;
    const unsigned short* brow = featb + (size_t)(c0 + m) * N + kb;

    f32x4 acc = {0.f, 0.f, 0.f, 0.f};
    #pragma unroll
    for (int k0 = 0; k0 < N; k0 += 32) {
        bf16x8 a = *(const bf16x8*)(arow + k0);
        bf16x8 b = *(const bf16x8*)(brow + k0);
        acc = __builtin_amdgcn_mfma_f32_16x16x32_bf16(a, b, acc, 0, 0, 0);
    }

    // C/D layout (verified m89/m91): col = lane&15, row = (lane>>4)*4 + reg
    const int col = c0 + (lane & 15);
    const int rowb = r0 + (lane >> 4) * 4;
    const float nc = sqn[col];
    #pragma unroll
    for (int r = 0; r < 4; ++r) {
        const int row = rowb + r;
        float sq = sqn[row] + nc - 2.f * acc[r];
        float v = (row == col) ? 0.f : -SIGMA * sqrtf(fmaxf(sq, 0.f));
        Fm[(size_t)row * N + col] = v;
    }
}

// ---------------------------------------------------------------------------
// Kernel 3: per-row fused softmax + denom + loss contribution.
// One block (512 threads) per row i; thread t owns column/index t.
// Row max is exactly 0 (diag F = 0, off-diag < 0) -> skip the max pass.
// ---------------------------------------------------------------------------
__global__ __launch_bounds__(512, 4)
void row_kernel(const float* __restrict__ Fm,
                const float* __restrict__ label,
                float* __restrict__ out) {
    const int i = blockIdx.x;
    const int t = threadIdx.x;   // 0..511
    const int wave = t >> 6, lane = t & 63;

    __shared__ __align__(16) float Rs[N];
    __shared__ __align__(16) float Ss[N];
    __shared__ float red[8];

    const float li = label[i];
    const float f = Fm[(size_t)i * N + t];
    const float Rk = fabsf(li - label[t]);
    Rs[t] = Rk;

    const float e = __expf(f);

    // --- softmax denominator Z = sum_j exp(f_j) (includes diagonal, exp(0)=1)
    float s = e;
    #pragma unroll
    for (int off = 32; off > 0; off >>= 1) s += __shfl_xor(s, off);
    if (lane == 0) red[wave] = s;
    __syncthreads();
    const float Z = red[0] + red[1] + red[2] + red[3] +
                    red[4] + red[5] + red[6] + red[7];

    float S = e / Z;
    if (t == i) S = 0.f;         // exclude j==i from all denom sums
    Ss[t] = S;
    __syncthreads();

    // --- denom[k=t] = sum_j [R[j] >= R[k]] * S[j], float4 LDS broadcasts
    float denom = 0.f;
    const float4* R4 = (const float4*)Rs;
    const float4* S4 = (const float4*)Ss;
    #pragma unroll 16
    for (int j4 = 0; j4 < N / 4; ++j4) {
        float4 r = R4[j4];
        float4 sv = S4[j4];
        denom += (r.x >= Rk) ? sv.x : 0.f;
        denom += (r.y >= Rk) ? sv.y : 0.f;
        denom += (r.z >= Rk) ? sv.z : 0.f;
        denom += (r.w >= Rk) ? sv.w : 0.f;
    }

    // --- per-k contribution; k==i excluded
    float part = (t == i) ? 0.f : (f - __logf(denom + EPS));

    // --- block reduce + single atomic
    #pragma unroll
    for (int off = 32; off > 0; off >>= 1) part += __shfl_xor(part, off);
    if (lane == 0) red[wave] = part;
    __syncthreads();
    if (t == 0) {
        float tot = red[0] + red[1] + red[2] + red[3] +
                    red[4] + red[5] + red[6] + red[7];
        atomicAdd(out, tot * (-1.f / ((float)N * (float)(N - 1))));
    }
}

// ---------------------------------------------------------------------------
extern "C" void kernel_launch(void* const* d_in, const int* in_sizes, int n_in,
                              void* d_out, int out_size, void* d_ws, size_t ws_size,
                              hipStream_t stream) {
    const float* feature = (const float*)d_in[0];   // [512, 512] f32
    const float* label   = (const float*)d_in[1];   // [512, 1]  f32
    float* out = (float*)d_out;

    // workspace layout (16B-aligned slices)
    float* Fm             = (float*)d_ws;                       // N*N f32 (1 MB)
    unsigned short* featb = (unsigned short*)(Fm + (size_t)N * N); // N*N bf16 (512 KB)
    float* sqn            = (float*)(featb + (size_t)N * N);    // N f32

    convert_kernel<<<N, 64, 0, stream>>>(feature, featb, sqn, out);
    {
        dim3 grid(N / 16, N / 16);
        fmat_mfma_kernel<<<grid, 64, 0, stream>>>(featb, sqn, Fm);
    }
    row_kernel<<<N, N, 0, stream>>>(Fm, label, out);
}